// Round 3
// baseline (173.525 us; speedup 1.0000x reference)
//
#include <hip/hip_runtime.h>

#define LOG2E 1.4426950408889634f
#define C2    2.8853900817779268f   // 2*log2(e)
#define NEGV  -1000000.0f

// Kernel 1: projection + exp precompute.
// Eq[b*512+q][h]   = exp2(clamp(C2 * (queries @ Wq), +-60))      (row-major)
// EkT[b][h][k]     = exp2(clamp(C2 * (keys    @ Wk), +-60))      (transposed!)
__global__ __launch_bounds__(256) void proj_exp_kernel(
    const float* __restrict__ queries,
    const float* __restrict__ keys,
    const float* __restrict__ Wq,
    const float* __restrict__ Wk,
    float* __restrict__ Eq,
    float* __restrict__ EkT)
{
    __shared__ float w_lds[64 * 64];
    __shared__ float in_lds[256];

    const int t   = threadIdx.x;
    const int blk = blockIdx.x;          // 0..2047
    const int r0  = blk * 4;             // virtual row among 8192
    const bool isQ = (r0 < 4096);
    const float* __restrict__ W  = isQ ? Wq : Wk;
    const float* __restrict__ in = isQ ? queries : keys;
    const int rbase = isQ ? r0 : (r0 - 4096);

#pragma unroll
    for (int i = 0; i < 16; ++i)
        w_lds[t + i * 256] = W[t + i * 256];
    in_lds[t] = in[(size_t)rbase * 64 + t];
    __syncthreads();

    const int h  = t & 63;
    const int rl = t >> 6;               // 0..3 local row
    float acc = 0.f;
#pragma unroll
    for (int i = 0; i < 64; ++i)
        acc = fmaf(in_lds[rl * 64 + i], w_lds[i * 64 + h], acc);

    float x = fminf(fmaxf(acc * C2, -60.f), 60.f);  // bounded: products < 2^120
    float e = __builtin_amdgcn_exp2f(x);
    const int row = rbase + rl;
    if (isQ) {
        Eq[(size_t)row * 64 + h] = e;
    } else {
        const int b  = row >> 9;
        const int kq = row & 511;
        EkT[((size_t)b * 64 + h) * 512 + kq] = e;   // scattered 4B stores; 1 MB total, one-time
    }
}

// Kernel 2: fused scores + softmax + PV.
// Block: 4 waves x 64 lanes handles 4 q-rows x all 512 k.
// Wave w owns k in [w*128, w*128+128); lane l owns k0 = w*128+2l and k0+1, ALL 4 q.
// score'[q][k] = -2 * sum_h wv[h] * rcp(1 + Eq[q][h]*EkT[h][k])   (softmax-invariant shift)
// Ek streams from global (coalesced float2, L2-resident); Eq via uniform LDS broadcast.
__global__ __launch_bounds__(256, 4) void attn_kernel(
    const float* __restrict__ Eq,
    const float* __restrict__ EkT,
    const float* __restrict__ wv,
    const float* __restrict__ V,
    const int* __restrict__ valid_lens,
    float* __restrict__ out)
{
    __shared__ float eq_lds[64 * 4];     // [h][q] transposed
    __shared__ float p_lds[4][512];
    __shared__ float part_lds[16 * 64];  // PV partials [kg*4+q][d]
    __shared__ float ws_lds[4][4];       // per-wave softmax partial sums [w][q]

    const int t   = threadIdx.x;
    const int bid = blockIdx.x;          // 0..1023
    const int b   = bid >> 7;
    const int q0  = (bid & 127) << 2;
    const int w   = t >> 6;              // wave 0..3
    const int l   = t & 63;              // lane
    const int vl  = valid_lens[b];

    // stage Eq transposed: [h][q], coalesced global read, one-time LDS write
    eq_lds[(t & 63) * 4 + (t >> 6)] = Eq[(size_t)(b * 512 + q0 + (t >> 6)) * 64 + (t & 63)];
    __syncthreads();

    const int k0 = w * 128 + 2 * l;      // this lane's k pair: k0, k0+1
    const float2* __restrict__ ek2 =
        reinterpret_cast<const float2*>(EkT + (size_t)b * 64 * 512) + (w * 64 + l);  // + 256*h per h

    float acc[4][2] = {{0.f,0.f},{0.f,0.f},{0.f,0.f},{0.f,0.f}};

#pragma unroll
    for (int hc = 0; hc < 4; ++hc) {
        float2 ek[16];
#pragma unroll
        for (int hh = 0; hh < 16; ++hh)
            ek[hh] = ek2[(size_t)(hc * 16 + hh) * 256];
#pragma unroll
        for (int hh = 0; hh < 16; ++hh) {
            const int h = hc * 16 + hh;
            float4 eq4 = *reinterpret_cast<const float4*>(&eq_lds[h * 4]);  // uniform broadcast
            float wvh  = wv[h];                                             // scalar load
            float ex = ek[hh].x, ey = ek[hh].y;
            acc[0][0] = fmaf(wvh, __builtin_amdgcn_rcpf(fmaf(eq4.x, ex, 1.f)), acc[0][0]);
            acc[0][1] = fmaf(wvh, __builtin_amdgcn_rcpf(fmaf(eq4.x, ey, 1.f)), acc[0][1]);
            acc[1][0] = fmaf(wvh, __builtin_amdgcn_rcpf(fmaf(eq4.y, ex, 1.f)), acc[1][0]);
            acc[1][1] = fmaf(wvh, __builtin_amdgcn_rcpf(fmaf(eq4.y, ey, 1.f)), acc[1][1]);
            acc[2][0] = fmaf(wvh, __builtin_amdgcn_rcpf(fmaf(eq4.z, ex, 1.f)), acc[2][0]);
            acc[2][1] = fmaf(wvh, __builtin_amdgcn_rcpf(fmaf(eq4.z, ey, 1.f)), acc[2][1]);
            acc[3][0] = fmaf(wvh, __builtin_amdgcn_rcpf(fmaf(eq4.w, ex, 1.f)), acc[3][0]);
            acc[3][1] = fmaf(wvh, __builtin_amdgcn_rcpf(fmaf(eq4.w, ey, 1.f)), acc[3][1]);
        }
    }

    // p = exp2(score*log2e) WITHOUT max subtraction: |score| <= 2*sum|wv| ~ 26, fp32-safe;
    // masked positions get exp2(-1.44e6) == 0 exactly.
    float psum[4];
#pragma unroll
    for (int q = 0; q < 4; ++q) {
        float s0 = (k0     < vl) ? -2.f * acc[q][0] : NEGV;
        float s1 = (k0 + 1 < vl) ? -2.f * acc[q][1] : NEGV;
        float p0 = __builtin_amdgcn_exp2f(s0 * LOG2E);
        float p1 = __builtin_amdgcn_exp2f(s1 * LOG2E);
        float2 pp; pp.x = p0; pp.y = p1;
        *reinterpret_cast<float2*>(&p_lds[q][k0]) = pp;   // stride-2 lanes: conflict-free b64
        psum[q] = p0 + p1;
    }
#pragma unroll
    for (int off = 32; off > 0; off >>= 1) {
        psum[0] += __shfl_xor(psum[0], off);
        psum[1] += __shfl_xor(psum[1], off);
        psum[2] += __shfl_xor(psum[2], off);
        psum[3] += __shfl_xor(psum[3], off);
    }
    if (l == 0) {
        ws_lds[w][0] = psum[0]; ws_lds[w][1] = psum[1];
        ws_lds[w][2] = psum[2]; ws_lds[w][3] = psum[3];
    }
    __syncthreads();

    // PV: thread = (kg = w, d = l). Each V row loaded exactly once per block.
    const int kg = w;
    const int d  = l;
    const float* __restrict__ Vb = V + (size_t)b * 512 * 64;
    float a0 = 0.f, a1 = 0.f, a2 = 0.f, a3 = 0.f;
    const int kbeg = kg * 128;
#pragma unroll 4
    for (int kk = kbeg; kk < kbeg + 128; kk += 4) {
        float4 p0 = *reinterpret_cast<const float4*>(&p_lds[0][kk]);   // broadcast b128
        float4 p1 = *reinterpret_cast<const float4*>(&p_lds[1][kk]);
        float4 p2 = *reinterpret_cast<const float4*>(&p_lds[2][kk]);
        float4 p3 = *reinterpret_cast<const float4*>(&p_lds[3][kk]);
        float v0 = Vb[(size_t)(kk + 0) * 64 + d];
        float v1 = Vb[(size_t)(kk + 1) * 64 + d];
        float v2 = Vb[(size_t)(kk + 2) * 64 + d];
        float v3 = Vb[(size_t)(kk + 3) * 64 + d];
        a0 = fmaf(p0.x, v0, a0); a0 = fmaf(p0.y, v1, a0);
        a0 = fmaf(p0.z, v2, a0); a0 = fmaf(p0.w, v3, a0);
        a1 = fmaf(p1.x, v0, a1); a1 = fmaf(p1.y, v1, a1);
        a1 = fmaf(p1.z, v2, a1); a1 = fmaf(p1.w, v3, a1);
        a2 = fmaf(p2.x, v0, a2); a2 = fmaf(p2.y, v1, a2);
        a2 = fmaf(p2.z, v2, a2); a2 = fmaf(p2.w, v3, a2);
        a3 = fmaf(p3.x, v0, a3); a3 = fmaf(p3.y, v1, a3);
        a3 = fmaf(p3.z, v2, a3); a3 = fmaf(p3.w, v3, a3);
    }
    part_lds[(kg * 4 + 0) * 64 + d] = a0;
    part_lds[(kg * 4 + 1) * 64 + d] = a1;
    part_lds[(kg * 4 + 2) * 64 + d] = a2;
    part_lds[(kg * 4 + 3) * 64 + d] = a3;
    __syncthreads();

    // combine: thread (q = w, d = l)
    const int q = w;
    float lsum = ws_lds[0][q] + ws_lds[1][q] + ws_lds[2][q] + ws_lds[3][q];
    float o = part_lds[(0 * 4 + q) * 64 + d] + part_lds[(1 * 4 + q) * 64 + d]
            + part_lds[(2 * 4 + q) * 64 + d] + part_lds[(3 * 4 + q) * 64 + d];
    out[(size_t)(b * 512 + q0 + q) * 64 + d] = o * __builtin_amdgcn_rcpf(lsum);
}

extern "C" void kernel_launch(void* const* d_in, const int* in_sizes, int n_in,
                              void* d_out, int out_size, void* d_ws, size_t ws_size,
                              hipStream_t stream) {
    (void)in_sizes; (void)n_in; (void)out_size; (void)ws_size;
    const float* queries = (const float*)d_in[0];
    const float* keys    = (const float*)d_in[1];
    const float* values  = (const float*)d_in[2];
    const int*   vlens   = (const int*)d_in[3];
    const float* Wq      = (const float*)d_in[4];
    const float* Wk      = (const float*)d_in[5];
    const float* wv      = (const float*)d_in[6];
    float* out = (float*)d_out;

    float* Eq  = (float*)d_ws;                // 8*512*64 floats = 1 MB
    float* EkT = Eq + 8 * 512 * 64;           // 1 MB, [b][h][k]

    proj_exp_kernel<<<2048, 256, 0, stream>>>(queries, keys, Wq, Wk, Eq, EkT);
    attn_kernel<<<1024, 256, 0, stream>>>(Eq, EkT, wv, values, vlens, out);
}

// Round 4
// 44.020 us; speedup vs baseline: 3.9419x; 3.9419x over previous
//
#include <hip/hip_runtime.h>

#define C2   2.8853900817779268f    //  2*log2(e)
#define NC2 -2.8853900817779268f    // -2*log2(e)

typedef unsigned int u32;
#define AS1 __attribute__((address_space(1)))
#define AS3 __attribute__((address_space(3)))

// Kernel 1: projection + exp precompute (round-2 proven version).
// Eq[b*512+q][h] = exp2(clamp(C2 * (queries @ Wq)[q][h], +-60)), Ek likewise (row-major).
__global__ __launch_bounds__(256) void proj_exp_kernel(
    const float* __restrict__ queries,
    const float* __restrict__ keys,
    const float* __restrict__ Wq,
    const float* __restrict__ Wk,
    float* __restrict__ Eq,
    float* __restrict__ Ek)
{
    __shared__ float w_lds[64 * 64];
    __shared__ float in_lds[256];

    const int t   = threadIdx.x;
    const int blk = blockIdx.x;          // 0..2047
    const int r0  = blk * 4;             // virtual row among 8192
    const bool isQ = (r0 < 4096);
    const float* __restrict__ W  = isQ ? Wq : Wk;
    const float* __restrict__ in = isQ ? queries : keys;
    float* __restrict__ Eo       = isQ ? Eq : Ek;
    const int rbase = isQ ? r0 : (r0 - 4096);

#pragma unroll
    for (int i = 0; i < 16; ++i)
        w_lds[t + i * 256] = W[t + i * 256];
    in_lds[t] = in[(size_t)rbase * 64 + t];
    __syncthreads();

    const int h  = t & 63;
    const int rl = t >> 6;               // 0..3 local row
    float acc = 0.f;
#pragma unroll
    for (int i = 0; i < 64; ++i)
        acc = fmaf(in_lds[rl * 64 + i], w_lds[i * 64 + h], acc);

    float x = fminf(fmaxf(acc * C2, -60.f), 60.f);  // bounded: products < 2^120
    Eo[(size_t)rbase * 64 + t] = __builtin_amdgcn_exp2f(x);
}

// Kernel 2: fused scores + softmax + PV.
// Block = 4 waves; wave w owns q-row q0+w; lane l owns k = kt*64+l.
// Ek staged via global_load_lds into XOR-swizzled double-buffered LDS tiles [64 k][32 h].
// score'[q][k] = -2 * sum_h wv[h] * rcp(1 + Eq[q][h]*Ek[k][h])   (softmax-invariant shift)
__global__ __launch_bounds__(256, 4) void attn_kernel(
    const float* __restrict__ Eq,
    const float* __restrict__ Ek,
    const float* __restrict__ wv,
    const float* __restrict__ V,
    const int* __restrict__ valid_lens,
    float* __restrict__ out)
{
    __shared__ float ek_lds[2][2048];    // 2 x (64 rows x 32 floats) = 2 x 8 KB, XOR-swizzled
    __shared__ float p_lds[4][512];
    __shared__ float ws_lds[4];          // per-q softmax denominators

    const int t   = threadIdx.x;
    const int bid = blockIdx.x;          // 0..1023
    const int b   = bid >> 7;
    const int q0  = (bid & 127) << 2;
    const int l   = t & 63;
    const int w   = __builtin_amdgcn_readfirstlane(threadIdx.x >> 6);  // provably uniform wave id
    const int vl  = valid_lens[b];

    const float* __restrict__ ekb = Ek + (size_t)b * 512 * 64;
    const float* __restrict__ eqp = Eq + (size_t)(b * 512 + q0 + w) * 64;  // wave-uniform -> s_load

    // ---- staging: tile (kt,hf) = rows [kt*64, +64), h cols [hf*32, +32)
    // LDS slot L (16B units) = (w*2+i)*64 + l ; row = L>>3 ; stored slot s_swz = L&7
    // holds global slot s_orig = (L&7) ^ (row&7)  (inverse == forward XOR swizzle)
    auto STAGE = [&](int kt, int hf, int bufb) {
        const float* base = ekb + (size_t)(kt * 64) * 64 + hf * 32;
#pragma unroll
        for (int i = 0; i < 2; ++i) {
            const int L   = (w * 2 + i) * 64 + l;
            const int row = L >> 3;
            const int so  = (L & 7) ^ (row & 7);
            const float* g = base + row * 64 + so * 4;
            __builtin_amdgcn_global_load_lds(
                (const AS1 u32*)g,
                (AS3 u32*)&ek_lds[bufb][(w * 2 + i) * 256],
                16, 0, 0);
        }
    };

    float acc  = 0.f;
    float psum = 0.f;

    STAGE(0, 0, 0);
    __syncthreads();                      // drains vmcnt -> tile 0 ready

#pragma unroll
    for (int j = 0; j < 16; ++j) {        // stage index: kt = j>>1, hf = j&1, buf = j&1
        const int kt = j >> 1;
        const int hf = j & 1;
        if (j < 15)
            STAGE((j + 1) >> 1, (j + 1) & 1, (j + 1) & 1);   // prefetch next into other buffer

        // compute from buf j&1: lane l = k-row l; 8 swizzled b128 reads
        {
            const char* ekc = (const char*)&ek_lds[hf /*==j&1*/][0] + l * 128;
            const int   swz = (l & 7) << 4;
#pragma unroll
            for (int s = 0; s < 8; ++s) {
                float4 e4 = *reinterpret_cast<const float4*>(ekc + ((s << 4) ^ swz));
                const int h = hf * 32 + s * 4;
                acc = fmaf(wv[h + 0], __builtin_amdgcn_rcpf(fmaf(eqp[h + 0], e4.x, 1.f)), acc);
                acc = fmaf(wv[h + 1], __builtin_amdgcn_rcpf(fmaf(eqp[h + 1], e4.y, 1.f)), acc);
                acc = fmaf(wv[h + 2], __builtin_amdgcn_rcpf(fmaf(eqp[h + 2], e4.z, 1.f)), acc);
                acc = fmaf(wv[h + 3], __builtin_amdgcn_rcpf(fmaf(eqp[h + 3], e4.w, 1.f)), acc);
            }
        }

        if (hf == 1) {
            const int k = kt * 64 + l;
            float p = (k < vl) ? __builtin_amdgcn_exp2f(acc * NC2) : 0.f;
            p_lds[w][k] = p;              // lanes consecutive: conflict-free b32
            psum += p;
            acc = 0.f;
        }
        __syncthreads();                  // next buffer ready (vmcnt drained), cur consumed
    }

    // full softmax denom for q = q0+w (lane l covered k = kt*64+l for all kt)
#pragma unroll
    for (int off = 32; off > 0; off >>= 1) psum += __shfl_xor(psum, off);
    if (l == 0) ws_lds[w] = psum;

    // ---- PV: wave w handles k-group [w*128, +128), lane = d column.
    // Each V row read exactly once per block (L2-resident across blocks).
    float* part = &ek_lds[0][0];          // alias: ek tiles dead, 4 KB partials [kg*4+q][d]
    const float* __restrict__ Vb = V + (size_t)b * 512 * 64;
    float a0 = 0.f, a1 = 0.f, a2 = 0.f, a3 = 0.f;
    const int kbeg = w * 128;
#pragma unroll 4
    for (int kk = kbeg; kk < kbeg + 128; kk += 4) {
        float4 p0 = *reinterpret_cast<const float4*>(&p_lds[0][kk]);   // uniform broadcast b128
        float4 p1 = *reinterpret_cast<const float4*>(&p_lds[1][kk]);
        float4 p2 = *reinterpret_cast<const float4*>(&p_lds[2][kk]);
        float4 p3 = *reinterpret_cast<const float4*>(&p_lds[3][kk]);
        float v0 = Vb[(size_t)(kk + 0) * 64 + l];
        float v1 = Vb[(size_t)(kk + 1) * 64 + l];
        float v2 = Vb[(size_t)(kk + 2) * 64 + l];
        float v3 = Vb[(size_t)(kk + 3) * 64 + l];
        a0 = fmaf(p0.x, v0, a0); a0 = fmaf(p0.y, v1, a0);
        a0 = fmaf(p0.z, v2, a0); a0 = fmaf(p0.w, v3, a0);
        a1 = fmaf(p1.x, v0, a1); a1 = fmaf(p1.y, v1, a1);
        a1 = fmaf(p1.z, v2, a1); a1 = fmaf(p1.w, v3, a1);
        a2 = fmaf(p2.x, v0, a2); a2 = fmaf(p2.y, v1, a2);
        a2 = fmaf(p2.z, v2, a2); a2 = fmaf(p2.w, v3, a2);
        a3 = fmaf(p3.x, v0, a3); a3 = fmaf(p3.y, v1, a3);
        a3 = fmaf(p3.z, v2, a3); a3 = fmaf(p3.w, v3, a3);
    }
    part[(w * 4 + 0) * 64 + l] = a0;
    part[(w * 4 + 1) * 64 + l] = a1;
    part[(w * 4 + 2) * 64 + l] = a2;
    part[(w * 4 + 3) * 64 + l] = a3;
    __syncthreads();

    // combine: wave w = q-row, lane l = d
    const float denom = ws_lds[w];
    float o = part[(0 * 4 + w) * 64 + l] + part[(1 * 4 + w) * 64 + l]
            + part[(2 * 4 + w) * 64 + l] + part[(3 * 4 + w) * 64 + l];
    out[(size_t)(b * 512 + q0 + w) * 64 + l] = o * __builtin_amdgcn_rcpf(denom);
}

extern "C" void kernel_launch(void* const* d_in, const int* in_sizes, int n_in,
                              void* d_out, int out_size, void* d_ws, size_t ws_size,
                              hipStream_t stream) {
    (void)in_sizes; (void)n_in; (void)out_size; (void)ws_size;
    const float* queries = (const float*)d_in[0];
    const float* keys    = (const float*)d_in[1];
    const float* values  = (const float*)d_in[2];
    const int*   vlens   = (const int*)d_in[3];
    const float* Wq      = (const float*)d_in[4];
    const float* Wk      = (const float*)d_in[5];
    const float* wv      = (const float*)d_in[6];
    float* out = (float*)d_out;

    float* Eq = (float*)d_ws;                 // 8*512*64 floats = 1 MB
    float* Ek = Eq + 8 * 512 * 64;            // 1 MB

    proj_exp_kernel<<<2048, 256, 0, stream>>>(queries, keys, Wq, Wk, Eq, Ek);
    attn_kernel<<<1024, 256, 0, stream>>>(Eq, Ek, wv, values, vlens, out);
}

// Round 5
// 37.196 us; speedup vs baseline: 4.6652x; 1.1835x over previous
//
#include <hip/hip_runtime.h>

#define C2   2.8853900817779268f    //  2*log2(e)
#define NC2 -2.8853900817779268f    // -2*log2(e)

// Kernel 1: projection + exp precompute.
// Eq[b*512+q][h] = exp2(clamp(C2 * (queries @ Wq)[q][h], +-60)), Ek likewise (row-major).
__global__ __launch_bounds__(256) void proj_exp_kernel(
    const float* __restrict__ queries,
    const float* __restrict__ keys,
    const float* __restrict__ Wq,
    const float* __restrict__ Wk,
    float* __restrict__ Eq,
    float* __restrict__ Ek)
{
    __shared__ float w_lds[64 * 64];
    __shared__ float in_lds[256];

    const int t   = threadIdx.x;
    const int blk = blockIdx.x;          // 0..2047
    const int r0  = blk * 4;             // virtual row among 8192
    const bool isQ = (r0 < 4096);
    const float* __restrict__ W  = isQ ? Wq : Wk;
    const float* __restrict__ in = isQ ? queries : keys;
    float* __restrict__ Eo       = isQ ? Eq : Ek;
    const int rbase = isQ ? r0 : (r0 - 4096);

#pragma unroll
    for (int i = 0; i < 16; ++i)
        w_lds[t + i * 256] = W[t + i * 256];
    in_lds[t] = in[(size_t)rbase * 64 + t];
    __syncthreads();

    const int h  = t & 63;
    const int rl = t >> 6;               // 0..3 local row
    float acc = 0.f;
#pragma unroll
    for (int i = 0; i < 64; ++i)
        acc = fmaf(in_lds[rl * 64 + i], w_lds[i * 64 + h], acc);

    float x = fminf(fmaxf(acc * C2, -60.f), 60.f);  // bounded: products < 2^120
    Eo[(size_t)rbase * 64 + t] = __builtin_amdgcn_exp2f(x);
}

// Kernel 2: fused scores + softmax + PV, register-resident Ek.
// Block = 8 waves x 64 lanes = 512 threads; covers ALL k (lane l of wave w owns
// k = w*64+l, its Ek row held in 64 VGPRs) for 8 q-rows.
// Inner loop is pure ALU: eq/wv are block-uniform (scalar operands), ek in VGPRs.
// score'[q][k] = -2 * sum_h wv[h] * rcp(1 + Eq[q][h]*Ek[k][h])   (softmax-invariant shift)
// p = exp2(score'*log2e) without max subtraction (|score'| <= 2*sum|wv| ~ 26, fp32-safe;
// masked k -> p = 0 exactly). Score and PV phases are wave-local: ONE barrier total.
__global__ __launch_bounds__(512, 4) void attn_kernel(
    const float* __restrict__ Eq,
    const float* __restrict__ Ek,
    const float* __restrict__ wv,
    const float* __restrict__ V,
    const int* __restrict__ valid_lens,
    float* __restrict__ out)
{
    __shared__ float p_lds[8][512];      // [q][k]
    __shared__ float part_lds[8 * 8 * 64]; // [w][q][d] PV partials
    __shared__ float wsum[8][8];         // [w][q] per-wave softmax partial sums

    const int t   = threadIdx.x;
    const int bid = blockIdx.x;          // 0..511
    const int b   = bid >> 6;
    const int q0  = (bid & 63) << 3;
    const int l   = t & 63;
    const int w   = __builtin_amdgcn_readfirstlane(threadIdx.x >> 6);  // uniform wave id
    const int vl  = valid_lens[b];
    const int k   = w * 64 + l;
    const bool kvalid = (k < vl);

    // ---- lane-resident Ek row: 64 VGPRs, loaded once (L2-resident)
    float ek[64];
    {
        const float4* ekr = reinterpret_cast<const float4*>(Ek + (size_t)(b * 512 + k) * 64);
#pragma unroll
        for (int i = 0; i < 16; ++i) {
            float4 v = ekr[i];
            ek[4 * i + 0] = v.x; ek[4 * i + 1] = v.y;
            ek[4 * i + 2] = v.z; ek[4 * i + 3] = v.w;
        }
    }

    const float* __restrict__ eqbase = Eq + (size_t)(b * 512 + q0) * 64;

    // ---- score + softmax numerators: zero LDS/VMEM in the inner loop
#pragma unroll 1
    for (int q = 0; q < 8; ++q) {
        const float* __restrict__ eqp = eqbase + q * 64;   // block-uniform -> scalar loads
        float a0 = 0.f, a1 = 0.f;
#pragma unroll
        for (int h = 0; h < 64; h += 2) {
            a0 = fmaf(wv[h + 0], __builtin_amdgcn_rcpf(fmaf(eqp[h + 0], ek[h + 0], 1.f)), a0);
            a1 = fmaf(wv[h + 1], __builtin_amdgcn_rcpf(fmaf(eqp[h + 1], ek[h + 1], 1.f)), a1);
        }
        float p = kvalid ? __builtin_amdgcn_exp2f((a0 + a1) * NC2) : 0.f;
        p_lds[q][k] = p;                 // consecutive lanes: conflict-free b32
        float ps = p;
#pragma unroll
        for (int off = 32; off > 0; off >>= 1) ps += __shfl_xor(ps, off);
        if (l == 0) wsum[w][q] = ps;
    }

    // ---- PV: wave w consumes ONLY its own k-chunk's p (self-written -> no barrier).
    // lane = d column; each V row read exactly once per block (coalesced, L2-resident).
    const float* __restrict__ Vb = V + (size_t)b * 512 * 64;
    float acc[8] = {0.f, 0.f, 0.f, 0.f, 0.f, 0.f, 0.f, 0.f};
    const int kb = w * 64;
#pragma unroll 4
    for (int kk = 0; kk < 64; kk += 4) {
        const int k0 = kb + kk;
        float4 pq[8];
#pragma unroll
        for (int q = 0; q < 8; ++q)
            pq[q] = *reinterpret_cast<const float4*>(&p_lds[q][k0]);   // uniform broadcast b128
        float v0 = Vb[(size_t)(k0 + 0) * 64 + l];
        float v1 = Vb[(size_t)(k0 + 1) * 64 + l];
        float v2 = Vb[(size_t)(k0 + 2) * 64 + l];
        float v3 = Vb[(size_t)(k0 + 3) * 64 + l];
#pragma unroll
        for (int q = 0; q < 8; ++q) {
            acc[q] = fmaf(pq[q].x, v0, acc[q]);
            acc[q] = fmaf(pq[q].y, v1, acc[q]);
            acc[q] = fmaf(pq[q].z, v2, acc[q]);
            acc[q] = fmaf(pq[q].w, v3, acc[q]);
        }
    }
#pragma unroll
    for (int q = 0; q < 8; ++q)
        part_lds[(w * 8 + q) * 64 + l] = acc[q];
    __syncthreads();                     // the kernel's only barrier

    // ---- combine: wave w owns output q-row w, lane = d
    float denom = 0.f, o = 0.f;
#pragma unroll
    for (int ww = 0; ww < 8; ++ww) {
        denom += wsum[ww][w];                         // uniform broadcast
        o     += part_lds[(ww * 8 + w) * 64 + l];     // consecutive lanes
    }
    out[(size_t)(b * 512 + q0 + w) * 64 + l] = o * __builtin_amdgcn_rcpf(denom);
}

extern "C" void kernel_launch(void* const* d_in, const int* in_sizes, int n_in,
                              void* d_out, int out_size, void* d_ws, size_t ws_size,
                              hipStream_t stream) {
    (void)in_sizes; (void)n_in; (void)out_size; (void)ws_size;
    const float* queries = (const float*)d_in[0];
    const float* keys    = (const float*)d_in[1];
    const float* values  = (const float*)d_in[2];
    const int*   vlens   = (const int*)d_in[3];
    const float* Wq      = (const float*)d_in[4];
    const float* Wk      = (const float*)d_in[5];
    const float* wv      = (const float*)d_in[6];
    float* out = (float*)d_out;

    float* Eq = (float*)d_ws;                 // 8*512*64 floats = 1 MB
    float* Ek = Eq + 8 * 512 * 64;            // 1 MB

    proj_exp_kernel<<<2048, 256, 0, stream>>>(queries, keys, Wq, Wk, Eq, Ek);
    attn_kernel<<<512, 512, 0, stream>>>(Eq, Ek, wv, values, vlens, out);
}